// Round 1
// baseline (680.942 us; speedup 1.0000x reference)
//
#include <hip/hip_runtime.h>
#include <hip/hip_bf16.h>
#include <math.h>

#define WX 32
#define WY 32
#define NTOK 1024
#define TD 1024
#define QKV 512
#define NH 8
#define HD 64
#define TOPK 32
#define BB 64

__device__ __forceinline__ float wred_sum(float v){
  #pragma unroll
  for (int o=32;o;o>>=1) v += __shfl_xor(v,o,64);
  return v;
}
__device__ __forceinline__ float wred_max(float v){
  #pragma unroll
  for (int o=32;o;o>>=1) v = fmaxf(v, __shfl_xor(v,o,64));
  return v;
}
__device__ __forceinline__ float dot4f(float4 a, float4 b){
  return a.x*b.x + a.y*b.y + a.z*b.z + a.w*b.w;
}

// ---------------- K1: per-token LN stats + scorer logits (one wave per token)
__global__ __launch_bounds__(256) void k1_stats(
    const float* __restrict__ x, const float* __restrict__ sw, const float* __restrict__ sb,
    float* __restrict__ mean, float* __restrict__ rstd, float* __restrict__ logit){
  int wave = threadIdx.x >> 6, lane = threadIdx.x & 63;
  int tok = blockIdx.x*4 + wave;                       // 0 .. B*N-1
  const float4* xp = (const float4*)(x + (size_t)tok*TD);
  const float4* sp = (const float4*)sw;
  float s1=0.f, s2=0.f, sd=0.f;
  #pragma unroll
  for (int j=0;j<4;j++){
    float4 v = xp[lane + j*64];
    float4 w = sp[lane + j*64];
    s1 += v.x+v.y+v.z+v.w;
    s2 += v.x*v.x + v.y*v.y + v.z*v.z + v.w*v.w;
    sd += dot4f(v,w);
  }
  s1 = wred_sum(s1); s2 = wred_sum(s2); sd = wred_sum(sd);
  if (lane==0){
    float m = s1*(1.f/1024.f);
    float var = s2*(1.f/1024.f) - m*m;
    mean[tok] = m;
    rstd[tok] = rsqrtf(var + 1e-5f);
    logit[tok] = sd + sb[0];
  }
}

// ---------------- K2: per-batch prep: argmax, s_n, q, u -> gu8/A/C0 (one block per b)
__global__ __launch_bounds__(256) void k2_prep(
    const float* __restrict__ x, const float* __restrict__ logit,
    const float* __restrict__ mean, const float* __restrict__ rstd,
    const float* __restrict__ lng, const float* __restrict__ lnb,
    const float* __restrict__ qkw, const float* __restrict__ qkb,
    int* __restrict__ selI, float* __restrict__ gu8,
    float* __restrict__ Aw, float* __restrict__ C0w){
  __shared__ float sn[TD];
  __shared__ float qs[QKV];
  __shared__ float redV[4]; __shared__ int redI[4];
  __shared__ float red16[64];
  __shared__ int sel_s;
  int b = blockIdx.x, t = threadIdx.x, lane = t&63, wave = t>>6;

  // argmax of logits[b, :]
  const float* lg = logit + b*NTOK;
  float bv = -INFINITY; int bi = 0;
  #pragma unroll
  for (int j=0;j<4;j++){ int idx = t*4+j; float v = lg[idx]; if (v > bv){ bv=v; bi=idx; } }
  #pragma unroll
  for (int o=32;o;o>>=1){
    float vv = __shfl_xor(bv,o,64); int ii = __shfl_xor(bi,o,64);
    if (vv > bv || (vv == bv && ii < bi)){ bv=vv; bi=ii; }
  }
  if (lane==0){ redV[wave]=bv; redI[wave]=bi; }
  __syncthreads();
  if (t==0){
    float v = redV[0]; int i = redI[0];
    for (int w=1; w<4; w++){ if (redV[w] > v || (redV[w]==v && redI[w]<i)){ v=redV[w]; i=redI[w]; } }
    sel_s = i; selI[b] = i;
  }
  __syncthreads();
  int sel = sel_s;
  float m = mean[b*NTOK+sel], r = rstd[b*NTOK+sel];
  float4 g4 = ((const float4*)lng)[t];
  float4 b4 = ((const float4*)lnb)[t];
  {
    float4 xv = ((const float4*)(x + ((size_t)b*NTOK + sel)*TD))[t];
    float4 s4;
    s4.x = (xv.x-m)*r*g4.x + b4.x;
    s4.y = (xv.y-m)*r*g4.y + b4.y;
    s4.z = (xv.z-m)*r*g4.z + b4.z;
    s4.w = (xv.w-m)*r*g4.w + b4.w;
    ((float4*)sn)[t] = s4;
  }
  __syncthreads();
  // q[j] = s_n . qk_w[j,:] + qk_b[j]
  #pragma unroll
  for (int rr=0; rr<2; rr++){
    int j = t + rr*256;
    const float4* wr = (const float4*)(qkw + (size_t)j*TD);
    float acc = 0.f;
    for (int d=0; d<256; d++) acc += dot4f(wr[d], ((const float4*)sn)[d]);
    qs[j] = acc + qkb[j];
  }
  __syncthreads();
  // u[h,d] = sum_c q[h*64+c]*qkw[h*64+c, d];   gu8 = u*g/8 ; A = sum(g*u)/8 ; C0 = (sum(b*u)+q.qb)/8
  float su[NH], bu[NH];
  #pragma unroll
  for (int h=0; h<NH; h++){
    float4 acc = make_float4(0.f,0.f,0.f,0.f);
    for (int c=0; c<HD; c++){
      float qv = qs[h*HD+c];
      float4 w = ((const float4*)(qkw + (size_t)(h*HD+c)*TD))[t];
      acc.x += qv*w.x; acc.y += qv*w.y; acc.z += qv*w.z; acc.w += qv*w.w;
    }
    su[h] = g4.x*acc.x + g4.y*acc.y + g4.z*acc.z + g4.w*acc.w;
    bu[h] = b4.x*acc.x + b4.y*acc.y + b4.z*acc.z + b4.w*acc.w;
    float4 gu;
    gu.x = acc.x*g4.x*0.125f; gu.y = acc.y*g4.y*0.125f;
    gu.z = acc.z*g4.z*0.125f; gu.w = acc.w*g4.w*0.125f;
    ((float4*)(gu8 + ((size_t)b*NH + h)*TD))[t] = gu;
  }
  #pragma unroll
  for (int h=0; h<NH; h++){ su[h] = wred_sum(su[h]); bu[h] = wred_sum(bu[h]); }
  if (lane==0){
    #pragma unroll
    for (int h=0; h<NH; h++){ red16[wave*16+h] = su[h]; red16[wave*16+8+h] = bu[h]; }
  }
  __syncthreads();
  if (t < NH){
    int h = t;
    float s = 0.f, bb = 0.f;
    for (int w=0; w<4; w++){ s += red16[w*16+h]; bb += red16[w*16+8+h]; }
    float qb = 0.f;
    for (int c=0; c<HD; c++) qb += qs[h*HD+c]*qkb[h*HD+c];
    Aw[b*NH+h] = s*0.125f;
    C0w[b*NH+h] = (bb + qb)*0.125f;
  }
}

// ---------------- K3: attention logits for all (b,h,n): second full stream of x
__global__ __launch_bounds__(128) void k3_attn(
    const float* __restrict__ x, const float* __restrict__ mean, const float* __restrict__ rstd,
    const float* __restrict__ gu8, const float* __restrict__ Aw, const float* __restrict__ C0w,
    const int* __restrict__ selI, const int* __restrict__ relIdx, const float* __restrict__ ub,
    float* __restrict__ attL){
  int b = blockIdx.x >> 3;
  int n = (blockIdx.x & 7)*128 + threadIdx.x;
  int tok = b*NTOK + n;
  float m = mean[tok], r = rstd[tok];
  int sel = selI[b];
  float bias = ub[relIdx[sel*NTOK + n]];
  const float4* xp = (const float4*)(x + (size_t)tok*TD);
  const float4* gp = (const float4*)(gu8 + (size_t)b*NH*TD);
  float4 acc[NH];
  #pragma unroll
  for (int h=0; h<NH; h++) acc[h] = make_float4(0.f,0.f,0.f,0.f);
  for (int d0=0; d0<256; d0+=4){
    #pragma unroll
    for (int jj=0; jj<4; jj++){
      float4 xv = xp[d0+jj];
      #pragma unroll
      for (int h=0; h<NH; h++){
        float4 g = gp[h*256 + d0 + jj];
        acc[h].x += xv.x*g.x; acc[h].y += xv.y*g.y;
        acc[h].z += xv.z*g.z; acc[h].w += xv.w*g.w;
      }
    }
  }
  #pragma unroll
  for (int h=0; h<NH; h++){
    float s = acc[h].x + acc[h].y + acc[h].z + acc[h].w;
    float L = r*s - r*m*Aw[b*NH+h] + C0w[b*NH+h] + bias;
    attL[((size_t)b*NH + h)*NTOK + n] = L;
  }
}

// ---------------- K4: per (b,h): softmax -> top-32 -> renorm -> weighted gather -> v_w matvec
__global__ __launch_bounds__(256) void k4_topkv(
    const float* __restrict__ x, const float* __restrict__ mean, const float* __restrict__ rstd,
    const float* __restrict__ lng, const float* __restrict__ lnb,
    const float* __restrict__ vw, const float* __restrict__ vb,
    const float* __restrict__ attL, float* __restrict__ yout){
  __shared__ float candV[4]; __shared__ int candI[4];
  __shared__ float redf[4];
  __shared__ float selV[TOPK]; __shared__ int selIs[TOPK];
  __shared__ float aa[TOPK]; __shared__ float am[TOPK];
  __shared__ float xbar[TD];
  __shared__ float red2[256];
  int b = blockIdx.x >> 3, h = blockIdx.x & 7;
  int t = threadIdx.x, lane = t&63, wave = t>>6;

  float4 Lv = ((const float4*)(attL + ((size_t)b*NH + h)*NTOK))[t];
  // global max
  float lm = fmaxf(fmaxf(Lv.x,Lv.y), fmaxf(Lv.z,Lv.w));
  lm = wred_max(lm);
  if (lane==0) redf[wave] = lm;
  __syncthreads();
  float maxL = fmaxf(fmaxf(redf[0],redf[1]), fmaxf(redf[2],redf[3]));
  __syncthreads();
  float ev[4];
  ev[0] = __expf(Lv.x - maxL); ev[1] = __expf(Lv.y - maxL);
  ev[2] = __expf(Lv.z - maxL); ev[3] = __expf(Lv.w - maxL);
  float zp = ev[0]+ev[1]+ev[2]+ev[3];
  zp = wred_sum(zp);
  if (lane==0) redf[wave] = zp;
  __syncthreads();
  float Z = redf[0]+redf[1]+redf[2]+redf[3];
  __syncthreads();

  // iterative top-32 (exp is monotone in logit; ties -> lowest index like lax.top_k)
  float S = 0.f;
  for (int k=0; k<TOPK; k++){
    float bv = -1.f; int bi = 1<<20;
    #pragma unroll
    for (int j=0;j<4;j++){ if (ev[j] > bv){ bv = ev[j]; bi = t*4+j; } }
    #pragma unroll
    for (int o=32;o;o>>=1){
      float vv = __shfl_xor(bv,o,64); int ii = __shfl_xor(bi,o,64);
      if (vv > bv || (vv == bv && ii < bi)){ bv=vv; bi=ii; }
    }
    if (lane==0){ candV[wave]=bv; candI[wave]=bi; }
    __syncthreads();
    float wv = candV[0]; int wi = candI[0];
    #pragma unroll
    for (int w=1; w<4; w++){
      float vv = candV[w]; int ii = candI[w];
      if (vv > wv || (vv == wv && ii < wi)){ wv=vv; wi=ii; }
    }
    if ((wi>>2) == t) ev[wi&3] = -1.f;
    if (t==0){ selV[k]=wv; selIs[k]=wi; }
    S += wv;
    __syncthreads();
  }

  float denom = S + 1e-9f*Z;       // == (sum_topk p + 1e-9) * Z
  float W = S/denom;               // sum of renormalized weights
  if (t < TOPK){
    int ni = selIs[t];
    float w = selV[t]/denom;
    float a = w * rstd[b*NTOK+ni];
    aa[t] = a; am[t] = a*mean[b*NTOK+ni];
  }
  __syncthreads();
  float c = 0.f;
  #pragma unroll
  for (int k=0;k<TOPK;k++) c += am[k];

  // xbar = g*(sum_k a_k x[n_k] - c) + b*W
  float4 acc = make_float4(0.f,0.f,0.f,0.f);
  for (int k=0;k<TOPK;k++){
    float a = aa[k];
    float4 xv = ((const float4*)(x + ((size_t)b*NTOK + selIs[k])*TD))[t];
    acc.x += a*xv.x; acc.y += a*xv.y; acc.z += a*xv.z; acc.w += a*xv.w;
  }
  float4 g4 = ((const float4*)lng)[t];
  float4 b4 = ((const float4*)lnb)[t];
  float4 xb;
  xb.x = g4.x*(acc.x - c) + b4.x*W;
  xb.y = g4.y*(acc.y - c) + b4.y*W;
  xb.z = g4.z*(acc.z - c) + b4.z*W;
  xb.w = g4.w*(acc.w - c) + b4.w*W;
  ((float4*)xbar)[t] = xb;
  __syncthreads();

  // y[b, h*64+co] = v_w[h*64+co,:] . xbar + v_b*W
  int co = t >> 2, part = t & 3;
  const float4* vp = (const float4*)(vw + (size_t)(h*HD+co)*TD + part*256);
  const float4* xp2 = ((const float4*)xbar) + part*64;
  float a2 = 0.f;
  for (int j=0;j<64;j++) a2 += dot4f(vp[j], xp2[j]);
  red2[t] = a2;
  __syncthreads();
  if (part==0){
    float y = red2[t] + red2[t+1] + red2[t+2] + red2[t+3] + vb[h*HD+co]*W;
    yout[b*QKV + h*HD + co] = y;
  }
}

// ---------------- K5: epilogue per batch: skip, relu, out_w, fc_w
__global__ __launch_bounds__(256) void k5_epi(
    const float* __restrict__ x, const int* __restrict__ selI,
    const float* __restrict__ skw, const float* __restrict__ skb,
    const float* __restrict__ ow, const float* __restrict__ ob,
    const float* __restrict__ fcw, const float* __restrict__ fcb,
    const float* __restrict__ yv, float* __restrict__ out){
  __shared__ float xs[TD];
  __shared__ float t1[QKV];
  __shared__ float t2[QKV];
  __shared__ float redA[4]; __shared__ float redB[4];
  int b = blockIdx.x, t = threadIdx.x, lane = t&63, wave = t>>6;
  int sel = selI[b];
  ((float4*)xs)[t] = ((const float4*)(x + ((size_t)b*NTOK + sel)*TD))[t];
  __syncthreads();
  #pragma unroll
  for (int rr=0; rr<2; rr++){
    int j = t + rr*256;
    const float4* wr = (const float4*)(skw + (size_t)j*TD);
    float acc = 0.f;
    for (int d=0; d<256; d++) acc += dot4f(wr[d], ((const float4*)xs)[d]);
    t1[j] = fmaxf(yv[b*QKV + j] + acc + skb[j], 0.f);
  }
  __syncthreads();
  #pragma unroll
  for (int rr=0; rr<2; rr++){
    int j = t + rr*256;
    const float4* wr = (const float4*)(ow + (size_t)j*QKV);
    float acc = 0.f;
    for (int d=0; d<128; d++) acc += dot4f(wr[d], ((const float4*)t1)[d]);
    t2[j] = acc + ob[j];
  }
  __syncthreads();
  float a0 = 0.f, a1 = 0.f;
  #pragma unroll
  for (int rr=0; rr<2; rr++){
    int d = t + rr*256;
    float v = t2[d];
    a0 += v*fcw[d]; a1 += v*fcw[QKV+d];
  }
  a0 = wred_sum(a0); a1 = wred_sum(a1);
  if (lane==0){ redA[wave]=a0; redB[wave]=a1; }
  __syncthreads();
  if (t==0){
    out[b*2+0] = redA[0]+redA[1]+redA[2]+redA[3] + fcb[0];
    out[b*2+1] = redB[0]+redB[1]+redB[2]+redB[3] + fcb[1];
  }
}

extern "C" void kernel_launch(void* const* d_in, const int* in_sizes, int n_in,
                              void* d_out, int out_size, void* d_ws, size_t ws_size,
                              hipStream_t stream) {
  const float* x   = (const float*)d_in[0];
  const float* sw  = (const float*)d_in[1];
  const float* sb  = (const float*)d_in[2];
  const float* lng = (const float*)d_in[3];
  const float* lnb = (const float*)d_in[4];
  const float* qkw = (const float*)d_in[5];
  const float* qkb = (const float*)d_in[6];
  const float* vw  = (const float*)d_in[7];
  const float* vb  = (const float*)d_in[8];
  const float* skw = (const float*)d_in[9];
  const float* skb = (const float*)d_in[10];
  const float* ow  = (const float*)d_in[11];
  const float* ob  = (const float*)d_in[12];
  const float* fcw = (const float*)d_in[13];
  const float* fcb = (const float*)d_in[14];
  const float* ub  = (const float*)d_in[15];
  const int*   ri  = (const int*)d_in[16];
  float* out = (float*)d_out;

  float* wsf   = (float*)d_ws;
  float* logit = wsf;                    // 65536
  float* mean  = wsf + 65536;            // 65536
  float* rstd  = wsf + 131072;           // 65536
  int*   selI  = (int*)(wsf + 196608);   // 64
  float* gu8   = wsf + 196672;           // 524288
  float* Aw    = wsf + 720960;           // 512
  float* C0w   = wsf + 721472;           // 512
  float* attL  = wsf + 721984;           // 524288
  float* yv    = wsf + 1246272;          // 32768

  k1_stats<<<16384, 256, 0, stream>>>(x, sw, sb, mean, rstd, logit);
  k2_prep<<<BB, 256, 0, stream>>>(x, logit, mean, rstd, lng, lnb, qkw, qkb,
                                  selI, gu8, Aw, C0w);
  k3_attn<<<BB*8, 128, 0, stream>>>(x, mean, rstd, gu8, Aw, C0w, selI, ri, ub, attL);
  k4_topkv<<<BB*NH, 256, 0, stream>>>(x, mean, rstd, lng, lnb, vw, vb, attL, yv);
  k5_epi<<<BB, 256, 0, stream>>>(x, selI, skw, skb, ow, ob, fcw, fcb, yv, out);
}

// Round 2
// 557.001 us; speedup vs baseline: 1.2225x; 1.2225x over previous
//
#include <hip/hip_runtime.h>
#include <hip/hip_bf16.h>
#include <math.h>

#define WX 32
#define WY 32
#define NTOK 1024
#define TD 1024
#define QKV 512
#define NH 8
#define HD 64
#define TOPK 32
#define BB 64

__device__ __forceinline__ float wred_sum(float v){
  #pragma unroll
  for (int o=32;o;o>>=1) v += __shfl_xor(v,o,64);
  return v;
}
__device__ __forceinline__ float wred_max(float v){
  #pragma unroll
  for (int o=32;o;o>>=1) v = fmaxf(v, __shfl_xor(v,o,64));
  return v;
}
__device__ __forceinline__ float dot4f(float4 a, float4 b){
  return a.x*b.x + a.y*b.y + a.z*b.z + a.w*b.w;
}

// ---------------- K1: per-token LN stats + scorer logits (one wave per token)
__global__ __launch_bounds__(256) void k1_stats(
    const float* __restrict__ x, const float* __restrict__ sw, const float* __restrict__ sb,
    float* __restrict__ mean, float* __restrict__ rstd, float* __restrict__ logit){
  int wave = threadIdx.x >> 6, lane = threadIdx.x & 63;
  int tok = blockIdx.x*4 + wave;                       // 0 .. B*N-1
  const float4* xp = (const float4*)(x + (size_t)tok*TD);
  const float4* sp = (const float4*)sw;
  float s1=0.f, s2=0.f, sd=0.f;
  #pragma unroll
  for (int j=0;j<4;j++){
    float4 v = xp[lane + j*64];
    float4 w = sp[lane + j*64];
    s1 += v.x+v.y+v.z+v.w;
    s2 += v.x*v.x + v.y*v.y + v.z*v.z + v.w*v.w;
    sd += dot4f(v,w);
  }
  s1 = wred_sum(s1); s2 = wred_sum(s2); sd = wred_sum(sd);
  if (lane==0){
    float m = s1*(1.f/1024.f);
    float var = s2*(1.f/1024.f) - m*m;
    mean[tok] = m;
    rstd[tok] = rsqrtf(var + 1e-5f);
    logit[tok] = sd + sb[0];
  }
}

// ---------------- K2: per-(b,h) block: argmax, s_n, q[64], u -> gu8/A/C0 (+bias for h==0)
__global__ __launch_bounds__(256) void k2_prep(
    const float* __restrict__ x, const float* __restrict__ logit,
    const float* __restrict__ mean, const float* __restrict__ rstd,
    const float* __restrict__ lng, const float* __restrict__ lnb,
    const float* __restrict__ qkw, const float* __restrict__ qkb,
    const int* __restrict__ relIdx, const float* __restrict__ ub,
    int* __restrict__ selI, float* __restrict__ gu8,
    float* __restrict__ Aw, float* __restrict__ C0w, float* __restrict__ biasArr){
  __shared__ float sn[TD];
  __shared__ float qs[HD];
  __shared__ float red[256];
  __shared__ float redV[4]; __shared__ int redI[4];
  __shared__ int sel_s;
  int b = blockIdx.x >> 3, h = blockIdx.x & 7;
  int t = threadIdx.x, lane = t&63, wave = t>>6;

  // argmax of logits[b, :] (redundant per head-block; 4 KB read)
  const float* lg = logit + b*NTOK;
  float bv = -INFINITY; int bi = 0;
  #pragma unroll
  for (int j=0;j<4;j++){ int idx = t*4+j; float v = lg[idx]; if (v > bv){ bv=v; bi=idx; } }
  #pragma unroll
  for (int o=32;o;o>>=1){
    float vv = __shfl_xor(bv,o,64); int ii = __shfl_xor(bi,o,64);
    if (vv > bv || (vv == bv && ii < bi)){ bv=vv; bi=ii; }
  }
  if (lane==0){ redV[wave]=bv; redI[wave]=bi; }
  __syncthreads();
  if (t==0){
    float v = redV[0]; int i = redI[0];
    for (int w=1; w<4; w++){ if (redV[w] > v || (redV[w]==v && redI[w]<i)){ v=redV[w]; i=redI[w]; } }
    sel_s = i;
    if (h==0) selI[b] = i;
  }
  __syncthreads();
  int sel = sel_s;
  float m = mean[b*NTOK+sel], r = rstd[b*NTOK+sel];
  float4 g4 = ((const float4*)lng)[t];
  float4 b4 = ((const float4*)lnb)[t];
  {
    float4 xv = ((const float4*)(x + ((size_t)b*NTOK + sel)*TD))[t];
    float4 s4;
    s4.x = (xv.x-m)*r*g4.x + b4.x;
    s4.y = (xv.y-m)*r*g4.y + b4.y;
    s4.z = (xv.z-m)*r*g4.z + b4.z;
    s4.w = (xv.w-m)*r*g4.w + b4.w;
    ((float4*)sn)[t] = s4;
  }
  __syncthreads();
  // q[c] for this head's 64 rows: 4 threads per row, 256 dims each
  {
    int row = t>>2, part = t&3;
    const float4* wr = (const float4*)(qkw + (size_t)(h*HD+row)*TD + part*256);
    const float4* xp = ((const float4*)sn) + part*64;
    float acc = 0.f;
    #pragma unroll 8
    for (int j=0;j<64;j++) acc += dot4f(wr[j], xp[j]);
    red[t] = acc;
  }
  __syncthreads();
  if (t < HD) qs[t] = red[t*4]+red[t*4+1]+red[t*4+2]+red[t*4+3] + qkb[h*HD+t];
  __syncthreads();
  // u[d] = sum_c qs[c]*qkw[h*64+c, d]; thread owns dims 4t..4t+3
  float4 acc = make_float4(0.f,0.f,0.f,0.f);
  for (int c=0;c<HD;c++){
    float qv = qs[c];
    float4 w = ((const float4*)(qkw + (size_t)(h*HD+c)*TD))[t];
    acc.x += qv*w.x; acc.y += qv*w.y; acc.z += qv*w.z; acc.w += qv*w.w;
  }
  {
    float4 gu;
    gu.x = acc.x*g4.x*0.125f; gu.y = acc.y*g4.y*0.125f;
    gu.z = acc.z*g4.z*0.125f; gu.w = acc.w*g4.w*0.125f;
    ((float4*)(gu8 + ((size_t)(b*NH+h))*TD))[t] = gu;
  }
  float su_p = g4.x*acc.x + g4.y*acc.y + g4.z*acc.z + g4.w*acc.w;
  float bu_p = b4.x*acc.x + b4.y*acc.y + b4.z*acc.z + b4.w*acc.w;
  su_p = wred_sum(su_p); bu_p = wred_sum(bu_p);
  if (lane==0){ red[wave] = su_p; red[8+wave] = bu_p; }
  if (wave==0){
    float qb_p = qs[lane]*qkb[h*HD+lane];
    qb_p = wred_sum(qb_p);
    if (lane==0) red[16] = qb_p;
  }
  __syncthreads();
  if (t==0){
    float s  = red[0]+red[1]+red[2]+red[3];
    float bb = red[8]+red[9]+red[10]+red[11];
    Aw[b*NH+h]  = s*0.125f;
    C0w[b*NH+h] = (bb + red[16])*0.125f;
  }
  if (h==0){
    const int* rp = relIdx + (size_t)sel*NTOK;
    #pragma unroll
    for (int j=0;j<4;j++){
      int n = t*4+j;
      biasArr[b*NTOK+n] = ub[rp[n]];
    }
  }
}

// ---------------- K3: attention logits; gu8 in registers, wave-per-token coalesced
__global__ __launch_bounds__(256) void k3_attn(
    const float* __restrict__ x, const float* __restrict__ mean, const float* __restrict__ rstd,
    const float* __restrict__ gu8, const float* __restrict__ Aw, const float* __restrict__ C0w,
    const float* __restrict__ biasArr, float* __restrict__ attL){
  int b = blockIdx.x >> 4;          // 16 blocks per batch
  int chunk = blockIdx.x & 15;      // 64 tokens per block
  int lane = threadIdx.x & 63, wave = threadIdx.x >> 6;

  const float4* gp = (const float4*)(gu8 + (size_t)b*NH*TD);
  float4 G[NH][4];
  #pragma unroll
  for (int h=0;h<NH;h++)
    #pragma unroll
    for (int j=0;j<4;j++)
      G[h][j] = gp[h*256 + j*64 + lane];
  float Ah[NH], Ch[NH];
  #pragma unroll
  for (int h=0;h<NH;h++){ Ah[h] = Aw[b*NH+h]; Ch[h] = C0w[b*NH+h]; }

  const int base = chunk*64 + wave*16;      // this wave's 16 tokens
  float4 cur[4];
  {
    const float4* xp = (const float4*)(x + ((size_t)b*NTOK + base)*TD);
    #pragma unroll
    for (int j=0;j<4;j++) cur[j] = xp[j*64 + lane];
  }
  for (int i=0;i<16;i++){
    int n = base + i;
    int tok = b*NTOK + n;
    float4 nxt[4];
    if (i < 15){
      const float4* xp = (const float4*)(x + (size_t)(tok+1)*TD);
      #pragma unroll
      for (int j=0;j<4;j++) nxt[j] = xp[j*64 + lane];
    }
    float m = mean[tok], r = rstd[tok], bias = biasArr[b*NTOK+n];
    float s[NH];
    #pragma unroll
    for (int h=0;h<NH;h++){
      float a = dot4f(cur[0],G[h][0]) + dot4f(cur[1],G[h][1])
              + dot4f(cur[2],G[h][2]) + dot4f(cur[3],G[h][3]);
      s[h] = wred_sum(a);
    }
    #pragma unroll
    for (int h=0;h<NH;h++){
      if (lane == h)
        attL[((size_t)b*NH+h)*NTOK + n] = r*s[h] - r*m*Ah[h] + Ch[h] + bias;
    }
    if (i < 15){
      #pragma unroll
      for (int j=0;j<4;j++) cur[j] = nxt[j];
    }
  }
}

// ---------------- K4: per (b,h): softmax -> per-wave top-32 + merge -> weighted gather -> v_w matvec
__global__ __launch_bounds__(256) void k4_topkv(
    const float* __restrict__ x, const float* __restrict__ mean, const float* __restrict__ rstd,
    const float* __restrict__ lng, const float* __restrict__ lnb,
    const float* __restrict__ vw, const float* __restrict__ vb,
    const float* __restrict__ attL, float* __restrict__ yout){
  __shared__ float redf[4];
  __shared__ float wtopV[4][TOPK]; __shared__ int wtopI[4][TOPK];
  __shared__ float selV[TOPK]; __shared__ int selIs[TOPK];
  __shared__ float Ssh;
  __shared__ float aa[TOPK]; __shared__ float am[TOPK];
  __shared__ float xbar[TD];
  __shared__ float red2[256];
  int b = blockIdx.x >> 3, h = blockIdx.x & 7;
  int t = threadIdx.x, lane = t&63, wave = t>>6;

  float4 Lv = ((const float4*)(attL + ((size_t)b*NH + h)*NTOK))[t];
  float lm = fmaxf(fmaxf(Lv.x,Lv.y), fmaxf(Lv.z,Lv.w));
  lm = wred_max(lm);
  if (lane==0) redf[wave] = lm;
  __syncthreads();
  float maxL = fmaxf(fmaxf(redf[0],redf[1]), fmaxf(redf[2],redf[3]));
  __syncthreads();
  float ev[4];
  ev[0] = __expf(Lv.x - maxL); ev[1] = __expf(Lv.y - maxL);
  ev[2] = __expf(Lv.z - maxL); ev[3] = __expf(Lv.w - maxL);
  float zp = ev[0]+ev[1]+ev[2]+ev[3];
  zp = wred_sum(zp);
  if (lane==0) redf[wave] = zp;
  __syncthreads();
  float Z = redf[0]+redf[1]+redf[2]+redf[3];

  // per-wave top-32, barrier-free (each wave owns 256 contiguous n = [256*wave, ...))
  for (int k=0;k<TOPK;k++){
    float bv = -1.f; int bi = 1<<20;
    #pragma unroll
    for (int j=0;j<4;j++){ if (ev[j] > bv){ bv = ev[j]; bi = t*4+j; } }
    #pragma unroll
    for (int o=32;o;o>>=1){
      float vv = __shfl_xor(bv,o,64); int ii = __shfl_xor(bi,o,64);
      if (vv > bv || (vv == bv && ii < bi)){ bv=vv; bi=ii; }
    }
    #pragma unroll
    for (int j=0;j<4;j++){ if (bi == t*4+j) ev[j] = -1.f; }
    if (lane==0){ wtopV[wave][k] = bv; wtopI[wave][k] = bi; }
  }
  __syncthreads();
  // 4-way sorted merge on thread 0
  if (t==0){
    int p0=0,p1=0,p2=0,p3=0;
    float S = 0.f;
    for (int k=0;k<TOPK;k++){
      float bv = -1.f; int bi = 1<<20, bw = 0;
      float v; int ii;
      v = wtopV[0][p0]; ii = wtopI[0][p0]; if (v > bv || (v==bv && ii<bi)){ bv=v; bi=ii; bw=0; }
      v = wtopV[1][p1]; ii = wtopI[1][p1]; if (v > bv || (v==bv && ii<bi)){ bv=v; bi=ii; bw=1; }
      v = wtopV[2][p2]; ii = wtopI[2][p2]; if (v > bv || (v==bv && ii<bi)){ bv=v; bi=ii; bw=2; }
      v = wtopV[3][p3]; ii = wtopI[3][p3]; if (v > bv || (v==bv && ii<bi)){ bv=v; bi=ii; bw=3; }
      if (bw==0) p0 = (p0<TOPK-1)?p0+1:p0;
      else if (bw==1) p1 = (p1<TOPK-1)?p1+1:p1;
      else if (bw==2) p2 = (p2<TOPK-1)?p2+1:p2;
      else p3 = (p3<TOPK-1)?p3+1:p3;
      selV[k] = bv; selIs[k] = bi; S += bv;
    }
    Ssh = S;
  }
  __syncthreads();
  float S = Ssh;
  float denom = S + 1e-9f*Z;       // == (sum_topk p + 1e-9) * Z
  float W = S/denom;               // sum of renormalized weights
  if (t < TOPK){
    int ni = selIs[t];
    float w = selV[t]/denom;
    float a = w * rstd[b*NTOK+ni];
    aa[t] = a; am[t] = a*mean[b*NTOK+ni];
  }
  __syncthreads();
  float c = 0.f;
  #pragma unroll
  for (int k=0;k<TOPK;k++) c += am[k];

  // xbar = g*(sum_k a_k x[n_k] - c) + b*W
  float4 acc = make_float4(0.f,0.f,0.f,0.f);
  for (int k=0;k<TOPK;k++){
    float a = aa[k];
    float4 xv = ((const float4*)(x + ((size_t)b*NTOK + selIs[k])*TD))[t];
    acc.x += a*xv.x; acc.y += a*xv.y; acc.z += a*xv.z; acc.w += a*xv.w;
  }
  float4 g4 = ((const float4*)lng)[t];
  float4 b4 = ((const float4*)lnb)[t];
  float4 xb;
  xb.x = g4.x*(acc.x - c) + b4.x*W;
  xb.y = g4.y*(acc.y - c) + b4.y*W;
  xb.z = g4.z*(acc.z - c) + b4.z*W;
  xb.w = g4.w*(acc.w - c) + b4.w*W;
  ((float4*)xbar)[t] = xb;
  __syncthreads();

  // y[b, h*64+co] = v_w[h*64+co,:] . xbar + v_b*W
  int co = t >> 2, part = t & 3;
  const float4* vp = (const float4*)(vw + (size_t)(h*HD+co)*TD + part*256);
  const float4* xp2 = ((const float4*)xbar) + part*64;
  float a2 = 0.f;
  #pragma unroll 8
  for (int j=0;j<64;j++) a2 += dot4f(vp[j], xp2[j]);
  red2[t] = a2;
  __syncthreads();
  if (part==0){
    float y = red2[t] + red2[t+1] + red2[t+2] + red2[t+3] + vb[h*HD+co]*W;
    yout[b*QKV + h*HD + co] = y;
  }
}

// ---------------- K5a: t1 = relu(y + skip) ; 8 blocks per batch (64 rows each)
__global__ __launch_bounds__(256) void k5a(
    const float* __restrict__ x, const int* __restrict__ selI,
    const float* __restrict__ skw, const float* __restrict__ skb,
    const float* __restrict__ yv, float* __restrict__ t1ws){
  __shared__ float xs[TD];
  __shared__ float red[256];
  int b = blockIdx.x >> 3, chunk = blockIdx.x & 7;
  int t = threadIdx.x;
  int sel = selI[b];
  ((float4*)xs)[t] = ((const float4*)(x + ((size_t)b*NTOK + sel)*TD))[t];
  __syncthreads();
  int row = chunk*64 + (t>>2), part = t&3;
  const float4* wr = (const float4*)(skw + (size_t)row*TD + part*256);
  const float4* xp = ((const float4*)xs) + part*64;
  float acc = 0.f;
  #pragma unroll 8
  for (int j=0;j<64;j++) acc += dot4f(wr[j], xp[j]);
  red[t] = acc;
  __syncthreads();
  if (part==0){
    float v = red[t]+red[t+1]+red[t+2]+red[t+3];
    t1ws[b*QKV+row] = fmaxf(yv[b*QKV+row] + v + skb[row], 0.f);
  }
}

// ---------------- K5b: t2 = t1 @ out_w^T + ob ; 8 blocks per batch
__global__ __launch_bounds__(256) void k5b(
    const float* __restrict__ t1ws, const float* __restrict__ ow,
    const float* __restrict__ ob, float* __restrict__ t2ws){
  __shared__ float ts[QKV];
  __shared__ float red[256];
  int b = blockIdx.x >> 3, chunk = blockIdx.x & 7;
  int t = threadIdx.x;
  if (t < 128) ((float4*)ts)[t] = ((const float4*)(t1ws + (size_t)b*QKV))[t];
  __syncthreads();
  int row = chunk*64 + (t>>2), part = t&3;
  const float4* wr = (const float4*)(ow + (size_t)row*QKV + part*128);
  const float4* xp = ((const float4*)ts) + part*32;
  float acc = 0.f;
  #pragma unroll
  for (int j=0;j<32;j++) acc += dot4f(wr[j], xp[j]);
  red[t] = acc;
  __syncthreads();
  if (part==0)
    t2ws[b*QKV+row] = red[t]+red[t+1]+red[t+2]+red[t+3] + ob[row];
}

// ---------------- K5c: out = t2 @ fc_w^T + fcb ; one wave per batch
__global__ __launch_bounds__(64) void k5c(
    const float* __restrict__ t2ws, const float* __restrict__ fcw,
    const float* __restrict__ fcb, float* __restrict__ out){
  int b = blockIdx.x, lane = threadIdx.x;
  float a0 = 0.f, a1 = 0.f;
  #pragma unroll
  for (int j=0;j<8;j++){
    int d = j*64 + lane;
    float v = t2ws[(size_t)b*QKV + d];
    a0 += v*fcw[d]; a1 += v*fcw[QKV+d];
  }
  a0 = wred_sum(a0); a1 = wred_sum(a1);
  if (lane==0){ out[b*2+0] = a0 + fcb[0]; out[b*2+1] = a1 + fcb[1]; }
}

extern "C" void kernel_launch(void* const* d_in, const int* in_sizes, int n_in,
                              void* d_out, int out_size, void* d_ws, size_t ws_size,
                              hipStream_t stream) {
  const float* x   = (const float*)d_in[0];
  const float* sw  = (const float*)d_in[1];
  const float* sb  = (const float*)d_in[2];
  const float* lng = (const float*)d_in[3];
  const float* lnb = (const float*)d_in[4];
  const float* qkw = (const float*)d_in[5];
  const float* qkb = (const float*)d_in[6];
  const float* vw  = (const float*)d_in[7];
  const float* vb  = (const float*)d_in[8];
  const float* skw = (const float*)d_in[9];
  const float* skb = (const float*)d_in[10];
  const float* ow  = (const float*)d_in[11];
  const float* ob  = (const float*)d_in[12];
  const float* fcw = (const float*)d_in[13];
  const float* fcb = (const float*)d_in[14];
  const float* ub  = (const float*)d_in[15];
  const int*   ri  = (const int*)d_in[16];
  float* out = (float*)d_out;

  float* wsf     = (float*)d_ws;
  float* logit   = wsf;                    // 65536
  float* mean    = wsf + 65536;            // 65536
  float* rstd    = wsf + 131072;           // 65536
  int*   selI    = (int*)(wsf + 196608);   // 64
  float* gu8     = wsf + 196672;           // 524288
  float* Aw      = wsf + 720960;           // 512
  float* C0w     = wsf + 721472;           // 512
  float* biasArr = wsf + 721984;           // 65536
  float* attL    = wsf + 787520;           // 524288
  float* yv      = wsf + 1311808;          // 32768
  float* t1ws    = wsf + 1344576;          // 32768
  float* t2ws    = wsf + 1377344;          // 32768

  k1_stats<<<16384, 256, 0, stream>>>(x, sw, sb, mean, rstd, logit);
  k2_prep<<<BB*NH, 256, 0, stream>>>(x, logit, mean, rstd, lng, lnb, qkw, qkb,
                                     ri, ub, selI, gu8, Aw, C0w, biasArr);
  k3_attn<<<BB*16, 256, 0, stream>>>(x, mean, rstd, gu8, Aw, C0w, biasArr, attL);
  k4_topkv<<<BB*NH, 256, 0, stream>>>(x, mean, rstd, lng, lnb, vw, vb, attL, yv);
  k5a<<<BB*8, 256, 0, stream>>>(x, selI, skw, skb, yv, t1ws);
  k5b<<<BB*8, 256, 0, stream>>>(t1ws, ow, ob, t2ws);
  k5c<<<BB, 64, 0, stream>>>(t2ws, fcw, fcb, out);
}